// Round 10
// baseline (926.960 us; speedup 1.0000x reference)
//
#include <hip/hip_runtime.h>
#include <hip/hip_bf16.h>

#define B_SZ 256
#define IN_  1024
#define E_   32
#define H1_  1024
#define S_   512
#define H2_  512
#define F_   64
#define T_   2048   // E_*F_
#define TIN_ 3072   // IN_+T_
#define NO_  16
#define HO_  512

typedef __attribute__((ext_vector_type(8))) short bf16x8;
typedef __attribute__((ext_vector_type(4))) float f32x4;

__device__ __forceinline__ unsigned short f2bf(float f) {
    unsigned u = __builtin_bit_cast(unsigned, f);
    u += 0x7fffu + ((u >> 16) & 1u);
    return (unsigned short)(u >> 16);
}
__device__ __forceinline__ float bf2f(unsigned short h) {
    return __builtin_bit_cast(float, ((unsigned)h) << 16);
}
__device__ __forceinline__ float softplusf(float x) {
    return fmaxf(x, 0.0f) + log1pf(expf(-fabsf(x)));
}
__device__ __forceinline__ void gload_lds16(const void* g, void* l) {
    __builtin_amdgcn_global_load_lds(
        (const __attribute__((address_space(1))) unsigned int*)g,
        (__attribute__((address_space(3))) unsigned int*)l,
        16, 0, 0);
}

// ------- merged weight convert+transpose: (K,N) f32 -> (N,K) bf16, 64x64 tiles --
__global__ __launch_bounds__(256) void cvt_all(
    const float* __restrict__ sw1, const float* __restrict__ sw2,
    const float* __restrict__ fw1, const float* __restrict__ fw2,
    unsigned short* __restrict__ w1t, unsigned short* __restrict__ w2t,
    unsigned short* __restrict__ f1t, unsigned short* __restrict__ f2t)
{
    __shared__ float tile[64][65];
    const int bx = blockIdx.x, e = blockIdx.y;
    const float* in; unsigned short* out; int K, N, kx, ny;
    if (bx < 768)      { in = sw1; out = w1t; K = TIN_; N = H1_; kx = bx % 48;        ny = bx / 48; }
    else if (bx < 896) { in = sw2; out = w2t; K = H1_;  N = S_;  kx = (bx-768) % 16;  ny = (bx-768) / 16; }
    else if (bx < 960) { in = fw1; out = f1t; K = S_;   N = H2_; kx = (bx-896) % 8;   ny = (bx-896) / 8; }
    else               { in = fw2; out = f2t; K = H2_;  N = F_;  kx = bx - 960;       ny = 0; }
    const size_t eoff = (size_t)e * K * N;
    const float* ip = in + eoff;
    unsigned short* op = out + eoff;
    const int k0 = kx * 64, n0 = ny * 64;
    const int t = threadIdx.x;
    const int lr = t >> 4;
    const int lc = (t & 15) << 2;
    #pragma unroll
    for (int i = 0; i < 4; ++i) {
        const float4 v = *(const float4*)&ip[(size_t)(k0 + lr + 16 * i) * N + n0 + lc];
        float* dst = &tile[lr + 16 * i][lc];
        dst[0] = v.x; dst[1] = v.y; dst[2] = v.z; dst[3] = v.w;
    }
    __syncthreads();
    #pragma unroll
    for (int i = 0; i < 4; ++i) {
        const int n = (t >> 4) + 16 * i;
        const int k = (t & 15) << 2;
        ushort4 o;
        o.x = f2bf(tile[k][n]); o.y = f2bf(tile[k + 1][n]);
        o.z = f2bf(tile[k + 2][n]); o.w = f2bf(tile[k + 3][n]);
        *(ushort4*)&op[(size_t)(n0 + n) * K + k0 + k] = o;
    }
}

// ------- x init: x_bf[:, T_:] = bf16(inputs), vectorized ------------------------
__global__ void x_init(const float* __restrict__ inp, unsigned short* __restrict__ x) {
    const int i = blockIdx.x * 256 + threadIdx.x;
    const int b = i / (IN_ / 4), c = (i % (IN_ / 4)) * 4;
    const float4 v = *(const float4*)&inp[(size_t)b * IN_ + c];
    ushort4 o;
    o.x = f2bf(v.x); o.y = f2bf(v.y); o.z = f2bf(v.z); o.w = f2bf(v.w);
    *(ushort4*)&x[(size_t)b * TIN_ + T_ + c] = o;
}

// ------- proven 2-phase batched per-expert bf16 MFMA GEMM (BK=32) ---------------
// C[e] (M x N) = act( A[e](M x Kslice) @ W[e]^T + bias [+ base(bf16)] )
// OUTM: 0 = bf16 out; 2 = bf16 pre-act out AND bf16 softplus out2
// PAIRED: 1-D grid, ids i and i+256 share (n,e) weight panel -> same XCD -> L2 reuse
template<int BM, int BN, int TPB, int WMT, int WNT, int ACT, int ADD_BASE, int OUTM, bool PAIRED>
__global__ __launch_bounds__(TPB) void gemm_k(
    const unsigned short* __restrict__ A, int lda, long strideAe,
    int kOff, int K,
    const unsigned short* __restrict__ W, int ldw, long strideWe,
    const float* __restrict__ bias,
    const unsigned short* __restrict__ baseBuf,
    void* __restrict__ out, void* __restrict__ out2,
    int ldc, long strideOe, int N)
{
    constexpr int MI = BM / (16 * WMT), NI = BN / (16 * WNT);
    constexpr int AL = (BM * 4) / TPB, BL = (BN * 4) / TPB;
    __shared__ unsigned short As0[BM * 32], Bs0[BN * 32];
    __shared__ unsigned short As1[BM * 32], Bs1[BN * 32];

    int e, m0, n0;
    if constexpr (PAIRED) {
        const int bid = blockIdx.x;
        const int NBn = N / BN;
        m0 = (bid >> 8) * BM;
        const int rem = bid & 255;
        n0 = (rem % NBn) * BN;
        e  = rem / NBn;
    } else {
        e = blockIdx.z; m0 = blockIdx.x * BM; n0 = blockIdx.y * BN;
    }

    const int tid = threadIdx.x;
    const int wid = tid >> 6;
    const int lane = tid & 63;
    const int wm = wid / WNT, wn = wid % WNT;
    const unsigned short* Ae = A + (size_t)e * strideAe + (size_t)m0 * lda + kOff;
    const unsigned short* We = W + (size_t)e * strideWe + (size_t)n0 * ldw + kOff;

    f32x4 acc[MI][NI];
    #pragma unroll
    for (int i = 0; i < MI; ++i)
        #pragma unroll
        for (int j = 0; j < NI; ++j) {
            f32x4 z = {0.f, 0.f, 0.f, 0.f};
            acc[i][j] = z;
        }
    const int lr = lane & 15;
    const int lk = (lane >> 4) << 3;

    auto stage = [&](unsigned short* Asb, unsigned short* Bsb, int kt) {
        const int kk = kt * 32;
        #pragma unroll
        for (int p = 0; p < AL; ++p) {
            const int seg = p * TPB + tid;
            const int r = seg >> 2, cc = (seg & 3) << 3;
            gload_lds16(Ae + (size_t)r * lda + kk + cc, Asb + ((size_t)(p * TPB + wid * 64)) * 8);
        }
        #pragma unroll
        for (int p = 0; p < BL; ++p) {
            const int seg = p * TPB + tid;
            const int r = seg >> 2, cc = (seg & 3) << 3;
            gload_lds16(We + (size_t)r * ldw + kk + cc, Bsb + ((size_t)(p * TPB + wid * 64)) * 8);
        }
    };
    auto compute = [&](const unsigned short* Asb, const unsigned short* Bsb) {
        bf16x8 af2[MI], bfv[NI];
        #pragma unroll
        for (int mi = 0; mi < MI; ++mi)
            af2[mi] = *(const bf16x8*)&Asb[(wm * MI * 16 + mi * 16 + lr) * 32 + lk];
        #pragma unroll
        for (int ni = 0; ni < NI; ++ni)
            bfv[ni] = *(const bf16x8*)&Bsb[(wn * NI * 16 + ni * 16 + lr) * 32 + lk];
        #pragma unroll
        for (int mi = 0; mi < MI; ++mi)
            #pragma unroll
            for (int ni = 0; ni < NI; ++ni)
                acc[mi][ni] = __builtin_amdgcn_mfma_f32_16x16x32_bf16(
                    af2[mi], bfv[ni], acc[mi][ni], 0, 0, 0);
    };

    const int nt = K / 32;
    stage(As0, Bs0, 0);
    __syncthreads();
    for (int t = 0; t < nt; t += 2) {
        stage(As1, Bs1, t + 1);
        compute(As0, Bs0);
        __syncthreads();
        if (t + 2 < nt) stage(As0, Bs0, t + 2);
        compute(As1, Bs1);
        __syncthreads();
    }

    // epilogue: D mapping col=lane&15, row=(lane>>4)*4+reg  [m89-verified]
    const int lg = lane >> 4;
    #pragma unroll
    for (int ni = 0; ni < NI; ++ni) {
        const int col = n0 + wn * NI * 16 + ni * 16 + lr;
        const float bv = bias ? bias[(size_t)e * N + col] : 0.0f;
        #pragma unroll
        for (int mi = 0; mi < MI; ++mi) {
            #pragma unroll
            for (int r = 0; r < 4; ++r) {
                const int row = m0 + wm * MI * 16 + mi * 16 + lg * 4 + r;
                float v = acc[mi][ni][r] + bv;
                if constexpr (ADD_BASE) v += bf2f(baseBuf[((size_t)e * B_SZ + row) * H1_ + col]);
                if constexpr (ACT == 1) v = softplusf(v);
                if constexpr (ACT == 2) v = fmaxf(v, 0.0f);
                const size_t oidx = (size_t)e * strideOe + (size_t)row * ldc + col;
                if constexpr (OUTM == 2) {
                    ((unsigned short*)out)[oidx] = f2bf(v);
                    ((unsigned short*)out2)[oidx] = f2bf(softplusf(v));
                } else {
                    ((unsigned short*)out)[oidx] = f2bf(v);
                }
            }
        }
    }
    (void)out2;
}

// ------- fused head: reward = relu(y@ow1+ob1) @ ow2 + ob2 -----------------------
__global__ __launch_bounds__(512) void head(const unsigned short* __restrict__ state,
                                            const float* __restrict__ ow1,
                                            const float* __restrict__ ob1,
                                            const float* __restrict__ ow2,
                                            const float* __restrict__ ob2,
                                            const int* __restrict__ actp,
                                            const int* __restrict__ ctxp,
                                            float* __restrict__ out) {
    __shared__ float ys[16][516];
    __shared__ float part[16][9];
    const int ctx = *ctxp;
    const float act = (float)(*actp);
    const int b0 = blockIdx.x * 16;
    const int t = threadIdx.x;   // 0..511
    for (int bb = 0; bb < 16; ++bb)
        ys[bb][1 + t] = bf2f(state[((size_t)(ctx * B_SZ + b0 + bb)) * S_ + t]);
    if (t < 16) ys[t][0] = act;
    __syncthreads();
    const float* w = ow1 + (size_t)ctx * (S_ + 1) * HO_;
    float accv[16];
    #pragma unroll
    for (int bb = 0; bb < 16; ++bb) accv[bb] = 0.0f;
    for (int k = 0; k < S_ + 1; ++k) {
        const float wv = w[(size_t)k * HO_ + t];
        #pragma unroll
        for (int bb = 0; bb < 16; ++bb) accv[bb] += ys[bb][k] * wv;
    }
    const float b1 = ob1[ctx * HO_ + t];
    const float w2v = ow2[(size_t)ctx * HO_ + t];
    const int lane = t & 63, wv8 = t >> 6;
    #pragma unroll
    for (int bb = 0; bb < 16; ++bb) {
        float s = fmaxf(accv[bb] + b1, 0.0f) * w2v;
        #pragma unroll
        for (int off = 32; off; off >>= 1) s += __shfl_down(s, off);
        if (lane == 0) part[bb][wv8] = s;
    }
    __syncthreads();
    if (t < 16) {
        float s = ob2[ctx];
        #pragma unroll
        for (int w8 = 0; w8 < 8; ++w8) s += part[t][w8];
        out[b0 + t] = s;
    }
}

extern "C" void kernel_launch(void* const* d_in, const int* in_sizes, int n_in,
                              void* d_out, int out_size, void* d_ws, size_t ws_size,
                              hipStream_t stream) {
    (void)in_sizes; (void)n_in; (void)out_size; (void)ws_size;
    const float* inputs = (const float*)d_in[0];
    const float* sw1 = (const float*)d_in[1];
    const float* sb1 = (const float*)d_in[2];
    const float* sw2 = (const float*)d_in[3];
    const float* sb2 = (const float*)d_in[4];
    const float* fw1 = (const float*)d_in[5];
    const float* fb1 = (const float*)d_in[6];
    const float* fw2 = (const float*)d_in[7];
    const float* fb2 = (const float*)d_in[8];
    const float* ow1 = (const float*)d_in[9];
    const float* ob1 = (const float*)d_in[10];
    const float* ow2 = (const float*)d_in[11];
    const float* ob2 = (const float*)d_in[12];
    const int* actp = (const int*)d_in[13];
    const int* ctxp = (const int*)d_in[14];

    char* p = (char*)d_ws;
    unsigned short* w1t = (unsigned short*)p; p += (size_t)E_ * H1_ * TIN_ * 2;
    unsigned short* w2t = (unsigned short*)p; p += (size_t)E_ * S_ * H1_ * 2;
    unsigned short* f1t = (unsigned short*)p; p += (size_t)E_ * H2_ * S_ * 2;
    unsigned short* f2t = (unsigned short*)p; p += (size_t)E_ * F_ * H2_ * 2;
    unsigned short* xbf = (unsigned short*)p; p += (size_t)B_SZ * TIN_ * 2;
    unsigned short* base = (unsigned short*)p; p += (size_t)E_ * B_SZ * H1_ * 2;
    unsigned short* hbf = (unsigned short*)p; p += (size_t)E_ * B_SZ * H1_ * 2;
    unsigned short* stbf = (unsigned short*)p; p += (size_t)E_ * B_SZ * S_ * 2;
    unsigned short* gbf = (unsigned short*)p; p += (size_t)E_ * B_SZ * H2_ * 2;

    cvt_all<<<dim3(968, E_), 256, 0, stream>>>(sw1, sw2, fw1, fw2, w1t, w2t, f1t, f2t);
    x_init<<<(B_SZ * IN_ / 4) / 256, 256, 0, stream>>>(inputs, xbf);

    // base = inputs @ sw1[:, T_:, :] + sb1 (bf16) ; h0 = softplus(base) fused
    // <128,128,TPB=256>: per-wave 64x64 (16 MFMA : 8 ds_read), grid 512, paired
    gemm_k<128, 128, 256, 2, 2, 0, 0, 2, true><<<dim3(512), 256, 0, stream>>>(
        xbf, TIN_, 0L, T_, IN_, w1t, TIN_, (long)H1_ * TIN_, sb1, nullptr,
        base, hbf, H1_, (long)B_SZ * H1_, H1_);

    for (int it = 0; it < 4; ++it) {
        if (it > 0) {
            gemm_k<128, 128, 256, 2, 2, 1, 1, 0, true><<<dim3(512), 256, 0, stream>>>(
                xbf, TIN_, 0L, 0, T_, w1t, TIN_, (long)H1_ * TIN_, nullptr, base,
                hbf, nullptr, H1_, (long)B_SZ * H1_, H1_);
        }
        // R6-proven configs below
        gemm_k<128, 64, 256, 2, 2, 0, 0, 0, true><<<dim3(512), 256, 0, stream>>>(
            hbf, H1_, (long)B_SZ * H1_, 0, H1_, w2t, H1_, (long)S_ * H1_, sb2, nullptr,
            stbf, nullptr, S_, (long)B_SZ * S_, S_);
        if (it < 3) {
            gemm_k<128, 64, 256, 2, 2, 2, 0, 0, true><<<dim3(512), 256, 0, stream>>>(
                stbf, S_, (long)B_SZ * S_, 0, S_, f1t, S_, (long)H2_ * S_, fb1, nullptr,
                gbf, nullptr, H2_, (long)B_SZ * H2_, H2_);
            // feat written straight into x_bf[:, :T_]  (out idx = e*64 + row*TIN_ + col)
            gemm_k<64, 64, 256, 2, 2, 0, 0, 0, false><<<dim3(4, 1, E_), 256, 0, stream>>>(
                gbf, H2_, (long)B_SZ * H2_, 0, H2_, f2t, H2_, (long)F_ * H2_, fb2, nullptr,
                xbf, nullptr, TIN_, 64L, F_);
        }
    }
    head<<<B_SZ / 16, 512, 0, stream>>>(stbf, ow1, ob1, ow2, ob2, actp, ctxp, (float*)d_out);
}

// Round 11
// 745.422 us; speedup vs baseline: 1.2435x; 1.2435x over previous
//
#include <hip/hip_runtime.h>
#include <hip/hip_bf16.h>

#define B_SZ 256
#define IN_  1024
#define E_   32
#define H1_  1024
#define S_   512
#define H2_  512
#define F_   64
#define T_   2048   // E_*F_
#define TIN_ 3072   // IN_+T_
#define NO_  16
#define HO_  512

typedef __attribute__((ext_vector_type(8))) short bf16x8;
typedef __attribute__((ext_vector_type(4))) float f32x4;

__device__ __forceinline__ unsigned short f2bf(float f) {
    unsigned u = __builtin_bit_cast(unsigned, f);
    u += 0x7fffu + ((u >> 16) & 1u);
    return (unsigned short)(u >> 16);
}
__device__ __forceinline__ float bf2f(unsigned short h) {
    return __builtin_bit_cast(float, ((unsigned)h) << 16);
}
__device__ __forceinline__ float softplusf(float x) {
    return fmaxf(x, 0.0f) + log1pf(expf(-fabsf(x)));
}
__device__ __forceinline__ void gload_lds16(const void* g, void* l) {
    __builtin_amdgcn_global_load_lds(
        (const __attribute__((address_space(1))) unsigned int*)g,
        (__attribute__((address_space(3))) unsigned int*)l,
        16, 0, 0);
}

// ------- weight convert + transpose: (K,N) f32 -> (N,K) bf16, 64x64 tiles -------
__global__ __launch_bounds__(256) void cvt_t64(const float* __restrict__ in,
                                               unsigned short* __restrict__ out,
                                               int K, int N) {
    __shared__ float tile[64][65];
    const size_t eoff = (size_t)blockIdx.z * K * N;
    const float* ip = in + eoff;
    unsigned short* op = out + eoff;
    const int k0 = blockIdx.x * 64, n0 = blockIdx.y * 64;
    const int t = threadIdx.x;
    const int lr = t >> 4;
    const int lc = (t & 15) << 2;
    #pragma unroll
    for (int i = 0; i < 4; ++i) {
        const float4 v = *(const float4*)&ip[(size_t)(k0 + lr + 16 * i) * N + n0 + lc];
        float* dst = &tile[lr + 16 * i][lc];
        dst[0] = v.x; dst[1] = v.y; dst[2] = v.z; dst[3] = v.w;
    }
    __syncthreads();
    #pragma unroll
    for (int i = 0; i < 4; ++i) {
        const int n = (t >> 4) + 16 * i;
        const int k = (t & 15) << 2;
        ushort4 o;
        o.x = f2bf(tile[k][n]); o.y = f2bf(tile[k + 1][n]);
        o.z = f2bf(tile[k + 2][n]); o.w = f2bf(tile[k + 3][n]);
        *(ushort4*)&op[(size_t)(n0 + n) * K + k0 + k] = o;
    }
}

// ------- x init: x_bf[:, T_:] = bf16(inputs), vectorized ------------------------
__global__ void x_init(const float* __restrict__ inp, unsigned short* __restrict__ x) {
    const int i = blockIdx.x * 256 + threadIdx.x;
    const int b = i / (IN_ / 4), c = (i % (IN_ / 4)) * 4;
    const float4 v = *(const float4*)&inp[(size_t)b * IN_ + c];
    ushort4 o;
    o.x = f2bf(v.x); o.y = f2bf(v.y); o.z = f2bf(v.z); o.w = f2bf(v.w);
    *(ushort4*)&x[(size_t)b * TIN_ + T_ + c] = o;
}

// ------- proven 2-phase batched per-expert bf16 MFMA GEMM -----------------------
// C[e] (M x N) = act( A[e](M x Kslice) @ W[e]^T + bias [+ base(bf16)] )
// OUTM: 0 = bf16 out; 2 = bf16 pre-act out AND bf16 softplus out2
// PAIRED: 1-D grid, ids i and i+256 share (n,e) weight panel -> same XCD -> L2 reuse
template<int BM, int BN, int TPB, int WMT, int WNT, int ACT, int ADD_BASE, int OUTM, bool PAIRED>
__global__ __launch_bounds__(TPB) void gemm_k(
    const unsigned short* __restrict__ A, int lda, long strideAe,
    int kOff, int K,
    const unsigned short* __restrict__ W, int ldw, long strideWe,
    const float* __restrict__ bias,
    const unsigned short* __restrict__ baseBuf,
    void* __restrict__ out, void* __restrict__ out2,
    int ldc, long strideOe, int N)
{
    constexpr int MI = BM / (16 * WMT), NI = BN / (16 * WNT);
    constexpr int AL = (BM * 4) / TPB, BL = (BN * 4) / TPB;
    __shared__ unsigned short As0[BM * 32], Bs0[BN * 32];
    __shared__ unsigned short As1[BM * 32], Bs1[BN * 32];

    int e, m0, n0;
    if constexpr (PAIRED) {
        const int bid = blockIdx.x;
        const int NBn = N / BN;
        m0 = (bid >> 8) * BM;
        const int rem = bid & 255;
        n0 = (rem % NBn) * BN;
        e  = rem / NBn;
    } else {
        e = blockIdx.z; m0 = blockIdx.x * BM; n0 = blockIdx.y * BN;
    }

    const int tid = threadIdx.x;
    const int wid = tid >> 6;
    const int lane = tid & 63;
    const int wm = wid / WNT, wn = wid % WNT;
    const unsigned short* Ae = A + (size_t)e * strideAe + (size_t)m0 * lda + kOff;
    const unsigned short* We = W + (size_t)e * strideWe + (size_t)n0 * ldw + kOff;

    f32x4 acc[MI][NI];
    #pragma unroll
    for (int i = 0; i < MI; ++i)
        #pragma unroll
        for (int j = 0; j < NI; ++j) {
            f32x4 z = {0.f, 0.f, 0.f, 0.f};
            acc[i][j] = z;
        }
    const int lr = lane & 15;
    const int lk = (lane >> 4) << 3;

    auto stage = [&](unsigned short* Asb, unsigned short* Bsb, int kt) {
        const int kk = kt * 32;
        #pragma unroll
        for (int p = 0; p < AL; ++p) {
            const int seg = p * TPB + tid;
            const int r = seg >> 2, cc = (seg & 3) << 3;
            gload_lds16(Ae + (size_t)r * lda + kk + cc, Asb + ((size_t)(p * TPB + wid * 64)) * 8);
        }
        #pragma unroll
        for (int p = 0; p < BL; ++p) {
            const int seg = p * TPB + tid;
            const int r = seg >> 2, cc = (seg & 3) << 3;
            gload_lds16(We + (size_t)r * ldw + kk + cc, Bsb + ((size_t)(p * TPB + wid * 64)) * 8);
        }
    };
    auto compute = [&](const unsigned short* Asb, const unsigned short* Bsb) {
        bf16x8 af2[MI], bfv[NI];
        #pragma unroll
        for (int mi = 0; mi < MI; ++mi)
            af2[mi] = *(const bf16x8*)&Asb[(wm * MI * 16 + mi * 16 + lr) * 32 + lk];
        #pragma unroll
        for (int ni = 0; ni < NI; ++ni)
            bfv[ni] = *(const bf16x8*)&Bsb[(wn * NI * 16 + ni * 16 + lr) * 32 + lk];
        #pragma unroll
        for (int mi = 0; mi < MI; ++mi)
            #pragma unroll
            for (int ni = 0; ni < NI; ++ni)
                acc[mi][ni] = __builtin_amdgcn_mfma_f32_16x16x32_bf16(
                    af2[mi], bfv[ni], acc[mi][ni], 0, 0, 0);
    };

    const int nt = K / 32;
    stage(As0, Bs0, 0);
    __syncthreads();
    for (int t = 0; t < nt; t += 2) {
        stage(As1, Bs1, t + 1);
        compute(As0, Bs0);
        __syncthreads();
        if (t + 2 < nt) stage(As0, Bs0, t + 2);
        compute(As1, Bs1);
        __syncthreads();
    }

    // epilogue: D mapping col=lane&15, row=(lane>>4)*4+reg  [m89-verified]
    const int lg = lane >> 4;
    #pragma unroll
    for (int ni = 0; ni < NI; ++ni) {
        const int col = n0 + wn * NI * 16 + ni * 16 + lr;
        const float bv = bias ? bias[(size_t)e * N + col] : 0.0f;
        #pragma unroll
        for (int mi = 0; mi < MI; ++mi) {
            #pragma unroll
            for (int r = 0; r < 4; ++r) {
                const int row = m0 + wm * MI * 16 + mi * 16 + lg * 4 + r;
                float v = acc[mi][ni][r] + bv;
                if constexpr (ADD_BASE) v += bf2f(baseBuf[((size_t)e * B_SZ + row) * H1_ + col]);
                if constexpr (ACT == 1) v = softplusf(v);
                if constexpr (ACT == 2) v = fmaxf(v, 0.0f);
                const size_t oidx = (size_t)e * strideOe + (size_t)row * ldc + col;
                if constexpr (OUTM == 2) {
                    ((unsigned short*)out)[oidx] = f2bf(v);
                    ((unsigned short*)out2)[oidx] = f2bf(softplusf(v));
                } else {
                    ((unsigned short*)out)[oidx] = f2bf(v);
                }
            }
        }
    }
    (void)out2;
}

// ------- head: z = relu(y @ ow1[ctx] + ob1[ctx]) --------------------------------
__global__ __launch_bounds__(512) void head_z(const unsigned short* __restrict__ state,
                                              const float* __restrict__ ow1,
                                              const float* __restrict__ ob1,
                                              const int* __restrict__ actp,
                                              const int* __restrict__ ctxp,
                                              float* __restrict__ z) {
    __shared__ float ys[16][516];
    const int ctx = *ctxp;
    const float act = (float)(*actp);
    const int b0 = blockIdx.x * 16;
    const int t = threadIdx.x;
    for (int bb = 0; bb < 16; ++bb)
        ys[bb][1 + t] = bf2f(state[((size_t)(ctx * B_SZ + b0 + bb)) * S_ + t]);
    if (t < 16) ys[t][0] = act;
    __syncthreads();
    const float* w = ow1 + (size_t)ctx * (S_ + 1) * HO_;
    float acc[16];
    #pragma unroll
    for (int bb = 0; bb < 16; ++bb) acc[bb] = 0.0f;
    for (int k = 0; k < S_ + 1; ++k) {
        const float wv = w[(size_t)k * HO_ + t];
        #pragma unroll
        for (int bb = 0; bb < 16; ++bb) acc[bb] += ys[bb][k] * wv;
    }
    const float b1 = ob1[ctx * HO_ + t];
    for (int bb = 0; bb < 16; ++bb)
        z[(size_t)(b0 + bb) * HO_ + t] = fmaxf(acc[bb] + b1, 0.0f);
}

// ------- head: reward = z @ ow2[ctx] + ob2[ctx] ---------------------------------
__global__ void head_r(const float* __restrict__ z, const float* __restrict__ ow2,
                       const float* __restrict__ ob2, const int* __restrict__ ctxp,
                       float* __restrict__ out) {
    const int ctx = *ctxp;
    const int b = blockIdx.x;
    const int t = threadIdx.x;
    const float* w = ow2 + (size_t)ctx * HO_;
    float s = 0.0f;
    for (int h = t; h < HO_; h += 64) s += z[(size_t)b * HO_ + h] * w[h];
    #pragma unroll
    for (int off = 32; off; off >>= 1) s += __shfl_down(s, off);
    if (t == 0) out[b] = s + ob2[ctx];
}

extern "C" void kernel_launch(void* const* d_in, const int* in_sizes, int n_in,
                              void* d_out, int out_size, void* d_ws, size_t ws_size,
                              hipStream_t stream) {
    (void)in_sizes; (void)n_in; (void)out_size; (void)ws_size;
    const float* inputs = (const float*)d_in[0];
    const float* sw1 = (const float*)d_in[1];
    const float* sb1 = (const float*)d_in[2];
    const float* sw2 = (const float*)d_in[3];
    const float* sb2 = (const float*)d_in[4];
    const float* fw1 = (const float*)d_in[5];
    const float* fb1 = (const float*)d_in[6];
    const float* fw2 = (const float*)d_in[7];
    const float* fb2 = (const float*)d_in[8];
    const float* ow1 = (const float*)d_in[9];
    const float* ob1 = (const float*)d_in[10];
    const float* ow2 = (const float*)d_in[11];
    const float* ob2 = (const float*)d_in[12];
    const int* actp = (const int*)d_in[13];
    const int* ctxp = (const int*)d_in[14];

    char* p = (char*)d_ws;
    unsigned short* w1t = (unsigned short*)p; p += (size_t)E_ * H1_ * TIN_ * 2;
    unsigned short* w2t = (unsigned short*)p; p += (size_t)E_ * S_ * H1_ * 2;
    unsigned short* f1t = (unsigned short*)p; p += (size_t)E_ * H2_ * S_ * 2;
    unsigned short* f2t = (unsigned short*)p; p += (size_t)E_ * F_ * H2_ * 2;
    unsigned short* xbf = (unsigned short*)p; p += (size_t)B_SZ * TIN_ * 2;
    unsigned short* base = (unsigned short*)p; p += (size_t)E_ * B_SZ * H1_ * 2;
    unsigned short* hbf = (unsigned short*)p; p += (size_t)E_ * B_SZ * H1_ * 2;
    unsigned short* stbf = (unsigned short*)p; p += (size_t)E_ * B_SZ * S_ * 2;
    unsigned short* gbf = (unsigned short*)p; p += (size_t)E_ * B_SZ * H2_ * 2;
    float* zbuf = (float*)p;                  p += (size_t)B_SZ * HO_ * 4;

    cvt_t64<<<dim3(TIN_ / 64, H1_ / 64, E_), 256, 0, stream>>>(sw1, w1t, TIN_, H1_);
    cvt_t64<<<dim3(H1_ / 64, S_ / 64, E_),  256, 0, stream>>>(sw2, w2t, H1_, S_);
    cvt_t64<<<dim3(S_ / 64, H2_ / 64, E_),  256, 0, stream>>>(fw1, f1t, S_, H2_);
    cvt_t64<<<dim3(H2_ / 64, F_ / 64, E_),  256, 0, stream>>>(fw2, f2t, H2_, F_);
    x_init<<<(B_SZ * IN_ / 4) / 256, 256, 0, stream>>>(inputs, xbf);

    // base = inputs @ sw1[:, T_:, :] + sb1 (bf16) ; h0 = softplus(base) fused
    // <128,128,512> 16 waves/CU, paired m-blocks share weight panel via L2
    gemm_k<128, 128, 512, 2, 4, 0, 0, 2, true><<<dim3(512), 512, 0, stream>>>(
        xbf, TIN_, 0L, T_, IN_, w1t, TIN_, (long)H1_ * TIN_, sb1, nullptr,
        base, hbf, H1_, (long)B_SZ * H1_, H1_);

    for (int it = 0; it < 4; ++it) {
        if (it > 0) {
            gemm_k<128, 128, 512, 2, 4, 1, 1, 0, true><<<dim3(512), 512, 0, stream>>>(
                xbf, TIN_, 0L, 0, T_, w1t, TIN_, (long)H1_ * TIN_, nullptr, base,
                hbf, nullptr, H1_, (long)B_SZ * H1_, H1_);
        }
        gemm_k<128, 64, 256, 2, 2, 0, 0, 0, true><<<dim3(512), 256, 0, stream>>>(
            hbf, H1_, (long)B_SZ * H1_, 0, H1_, w2t, H1_, (long)S_ * H1_, sb2, nullptr,
            stbf, nullptr, S_, (long)B_SZ * S_, S_);
        if (it < 3) {
            gemm_k<128, 64, 256, 2, 2, 2, 0, 0, true><<<dim3(512), 256, 0, stream>>>(
                stbf, S_, (long)B_SZ * S_, 0, S_, f1t, S_, (long)H2_ * S_, fb1, nullptr,
                gbf, nullptr, H2_, (long)B_SZ * H2_, H2_);
            // feat written straight into x_bf[:, :T_]  (out idx = e*64 + row*TIN_ + col)
            gemm_k<64, 64, 256, 2, 2, 0, 0, 0, false><<<dim3(4, 1, E_), 256, 0, stream>>>(
                gbf, H2_, (long)B_SZ * H2_, 0, H2_, f2t, H2_, (long)F_ * H2_, fb2, nullptr,
                xbf, nullptr, TIN_, 64L, F_);
        }
    }
    head_z<<<B_SZ / 16, 512, 0, stream>>>(stbf, ow1, ob1, actp, ctxp, zbuf);
    head_r<<<B_SZ, 64, 0, stream>>>(zbuf, ow2, ob2, ctxp, (float*)d_out);
}

// Round 12
// 743.390 us; speedup vs baseline: 1.2469x; 1.0027x over previous
//
#include <hip/hip_runtime.h>
#include <hip/hip_bf16.h>

#define B_SZ 256
#define IN_  1024
#define E_   32
#define H1_  1024
#define S_   512
#define H2_  512
#define F_   64
#define T_   2048   // E_*F_
#define TIN_ 3072   // IN_+T_
#define NO_  16
#define HO_  512

typedef __attribute__((ext_vector_type(8))) short bf16x8;
typedef __attribute__((ext_vector_type(4))) float f32x4;

__device__ __forceinline__ unsigned short f2bf(float f) {
    unsigned u = __builtin_bit_cast(unsigned, f);
    u += 0x7fffu + ((u >> 16) & 1u);
    return (unsigned short)(u >> 16);
}
__device__ __forceinline__ float bf2f(unsigned short h) {
    return __builtin_bit_cast(float, ((unsigned)h) << 16);
}
__device__ __forceinline__ float softplusf(float x) {
    return fmaxf(x, 0.0f) + log1pf(expf(-fabsf(x)));
}
__device__ __forceinline__ void gload_lds16(const void* g, void* l) {
    __builtin_amdgcn_global_load_lds(
        (const __attribute__((address_space(1))) unsigned int*)g,
        (__attribute__((address_space(3))) unsigned int*)l,
        16, 0, 0);
}

// ------- merged weight convert+transpose: (K,N) f32 -> (N,K) bf16, 64x64 tiles --
// bx decode: [0,768) sw1 (48x16), [768,896) sw2 (16x8), [896,960) fw1 (8x8),
//            [960,968) fw2 (8x1).  by = expert.  (verified R7/R9/R10)
__global__ __launch_bounds__(256) void cvt_all(
    const float* __restrict__ sw1, const float* __restrict__ sw2,
    const float* __restrict__ fw1, const float* __restrict__ fw2,
    unsigned short* __restrict__ w1t, unsigned short* __restrict__ w2t,
    unsigned short* __restrict__ f1t, unsigned short* __restrict__ f2t)
{
    __shared__ float tile[64][65];
    const int bx = blockIdx.x, e = blockIdx.y;
    const float* in; unsigned short* out; int K, N, kx, ny;
    if (bx < 768)      { in = sw1; out = w1t; K = TIN_; N = H1_; kx = bx % 48;        ny = bx / 48; }
    else if (bx < 896) { in = sw2; out = w2t; K = H1_;  N = S_;  kx = (bx-768) % 16;  ny = (bx-768) / 16; }
    else if (bx < 960) { in = fw1; out = f1t; K = S_;   N = H2_; kx = (bx-896) % 8;   ny = (bx-896) / 8; }
    else               { in = fw2; out = f2t; K = H2_;  N = F_;  kx = bx - 960;       ny = 0; }
    const size_t eoff = (size_t)e * K * N;
    const float* ip = in + eoff;
    unsigned short* op = out + eoff;
    const int k0 = kx * 64, n0 = ny * 64;
    const int t = threadIdx.x;
    const int lr = t >> 4;
    const int lc = (t & 15) << 2;
    #pragma unroll
    for (int i = 0; i < 4; ++i) {
        const float4 v = *(const float4*)&ip[(size_t)(k0 + lr + 16 * i) * N + n0 + lc];
        float* dst = &tile[lr + 16 * i][lc];
        dst[0] = v.x; dst[1] = v.y; dst[2] = v.z; dst[3] = v.w;
    }
    __syncthreads();
    #pragma unroll
    for (int i = 0; i < 4; ++i) {
        const int n = (t >> 4) + 16 * i;
        const int k = (t & 15) << 2;
        ushort4 o;
        o.x = f2bf(tile[k][n]); o.y = f2bf(tile[k + 1][n]);
        o.z = f2bf(tile[k + 2][n]); o.w = f2bf(tile[k + 3][n]);
        *(ushort4*)&op[(size_t)(n0 + n) * K + k0 + k] = o;
    }
}

// ------- x init: x_bf[:, T_:] = bf16(inputs), vectorized ------------------------
__global__ void x_init(const float* __restrict__ inp, unsigned short* __restrict__ x) {
    const int i = blockIdx.x * 256 + threadIdx.x;
    const int b = i / (IN_ / 4), c = (i % (IN_ / 4)) * 4;
    const float4 v = *(const float4*)&inp[(size_t)b * IN_ + c];
    ushort4 o;
    o.x = f2bf(v.x); o.y = f2bf(v.y); o.z = f2bf(v.z); o.w = f2bf(v.w);
    *(ushort4*)&x[(size_t)b * TIN_ + T_ + c] = o;
}

// ------- proven 2-phase batched per-expert bf16 MFMA GEMM (R6/R11-exact) --------
// C[e] (M x N) = act( A[e](M x Kslice) @ W[e]^T + bias [+ base(bf16)] )
// OUTM: 0 = bf16 out; 2 = bf16 pre-act out AND bf16 softplus out2
// PAIRED: 1-D grid, ids i and i+256 share (n,e) weight panel -> same XCD -> L2 reuse
template<int BM, int BN, int TPB, int WMT, int WNT, int ACT, int ADD_BASE, int OUTM, bool PAIRED>
__global__ __launch_bounds__(TPB) void gemm_k(
    const unsigned short* __restrict__ A, int lda, long strideAe,
    int kOff, int K,
    const unsigned short* __restrict__ W, int ldw, long strideWe,
    const float* __restrict__ bias,
    const unsigned short* __restrict__ baseBuf,
    void* __restrict__ out, void* __restrict__ out2,
    int ldc, long strideOe, int N)
{
    constexpr int MI = BM / (16 * WMT), NI = BN / (16 * WNT);
    constexpr int AL = (BM * 4) / TPB, BL = (BN * 4) / TPB;
    __shared__ unsigned short As0[BM * 32], Bs0[BN * 32];
    __shared__ unsigned short As1[BM * 32], Bs1[BN * 32];

    int e, m0, n0;
    if constexpr (PAIRED) {
        const int bid = blockIdx.x;
        const int NBn = N / BN;
        m0 = (bid >> 8) * BM;
        const int rem = bid & 255;
        n0 = (rem % NBn) * BN;
        e  = rem / NBn;
    } else {
        e = blockIdx.z; m0 = blockIdx.x * BM; n0 = blockIdx.y * BN;
    }

    const int tid = threadIdx.x;
    const int wid = tid >> 6;
    const int lane = tid & 63;
    const int wm = wid / WNT, wn = wid % WNT;
    const unsigned short* Ae = A + (size_t)e * strideAe + (size_t)m0 * lda + kOff;
    const unsigned short* We = W + (size_t)e * strideWe + (size_t)n0 * ldw + kOff;

    f32x4 acc[MI][NI];
    #pragma unroll
    for (int i = 0; i < MI; ++i)
        #pragma unroll
        for (int j = 0; j < NI; ++j) {
            f32x4 z = {0.f, 0.f, 0.f, 0.f};
            acc[i][j] = z;
        }
    const int lr = lane & 15;
    const int lk = (lane >> 4) << 3;

    auto stage = [&](unsigned short* Asb, unsigned short* Bsb, int kt) {
        const int kk = kt * 32;
        #pragma unroll
        for (int p = 0; p < AL; ++p) {
            const int seg = p * TPB + tid;
            const int r = seg >> 2, cc = (seg & 3) << 3;
            gload_lds16(Ae + (size_t)r * lda + kk + cc, Asb + ((size_t)(p * TPB + wid * 64)) * 8);
        }
        #pragma unroll
        for (int p = 0; p < BL; ++p) {
            const int seg = p * TPB + tid;
            const int r = seg >> 2, cc = (seg & 3) << 3;
            gload_lds16(We + (size_t)r * ldw + kk + cc, Bsb + ((size_t)(p * TPB + wid * 64)) * 8);
        }
    };
    auto compute = [&](const unsigned short* Asb, const unsigned short* Bsb) {
        bf16x8 af2[MI], bfv[NI];
        #pragma unroll
        for (int mi = 0; mi < MI; ++mi)
            af2[mi] = *(const bf16x8*)&Asb[(wm * MI * 16 + mi * 16 + lr) * 32 + lk];
        #pragma unroll
        for (int ni = 0; ni < NI; ++ni)
            bfv[ni] = *(const bf16x8*)&Bsb[(wn * NI * 16 + ni * 16 + lr) * 32 + lk];
        #pragma unroll
        for (int mi = 0; mi < MI; ++mi)
            #pragma unroll
            for (int ni = 0; ni < NI; ++ni)
                acc[mi][ni] = __builtin_amdgcn_mfma_f32_16x16x32_bf16(
                    af2[mi], bfv[ni], acc[mi][ni], 0, 0, 0);
    };

    const int nt = K / 32;
    stage(As0, Bs0, 0);
    __syncthreads();
    for (int t = 0; t < nt; t += 2) {
        stage(As1, Bs1, t + 1);
        compute(As0, Bs0);
        __syncthreads();
        if (t + 2 < nt) stage(As0, Bs0, t + 2);
        compute(As1, Bs1);
        __syncthreads();
    }

    // epilogue: D mapping col=lane&15, row=(lane>>4)*4+reg  [m89-verified]
    const int lg = lane >> 4;
    #pragma unroll
    for (int ni = 0; ni < NI; ++ni) {
        const int col = n0 + wn * NI * 16 + ni * 16 + lr;
        const float bv = bias ? bias[(size_t)e * N + col] : 0.0f;
        #pragma unroll
        for (int mi = 0; mi < MI; ++mi) {
            #pragma unroll
            for (int r = 0; r < 4; ++r) {
                const int row = m0 + wm * MI * 16 + mi * 16 + lg * 4 + r;
                float v = acc[mi][ni][r] + bv;
                if constexpr (ADD_BASE) v += bf2f(baseBuf[((size_t)e * B_SZ + row) * H1_ + col]);
                if constexpr (ACT == 1) v = softplusf(v);
                if constexpr (ACT == 2) v = fmaxf(v, 0.0f);
                const size_t oidx = (size_t)e * strideOe + (size_t)row * ldc + col;
                if constexpr (OUTM == 2) {
                    ((unsigned short*)out)[oidx] = f2bf(v);
                    ((unsigned short*)out2)[oidx] = f2bf(softplusf(v));
                } else {
                    ((unsigned short*)out)[oidx] = f2bf(v);
                }
            }
        }
    }
    (void)out2;
}

// ------- fused head: reward = relu(y@ow1+ob1) @ ow2 + ob2 (verified R7) ---------
__global__ __launch_bounds__(512) void head(const unsigned short* __restrict__ state,
                                            const float* __restrict__ ow1,
                                            const float* __restrict__ ob1,
                                            const float* __restrict__ ow2,
                                            const float* __restrict__ ob2,
                                            const int* __restrict__ actp,
                                            const int* __restrict__ ctxp,
                                            float* __restrict__ out) {
    __shared__ float ys[16][516];
    __shared__ float part[16][9];
    const int ctx = *ctxp;
    const float act = (float)(*actp);
    const int b0 = blockIdx.x * 16;
    const int t = threadIdx.x;   // 0..511
    for (int bb = 0; bb < 16; ++bb)
        ys[bb][1 + t] = bf2f(state[((size_t)(ctx * B_SZ + b0 + bb)) * S_ + t]);
    if (t < 16) ys[t][0] = act;
    __syncthreads();
    const float* w = ow1 + (size_t)ctx * (S_ + 1) * HO_;
    float accv[16];
    #pragma unroll
    for (int bb = 0; bb < 16; ++bb) accv[bb] = 0.0f;
    for (int k = 0; k < S_ + 1; ++k) {
        const float wv = w[(size_t)k * HO_ + t];
        #pragma unroll
        for (int bb = 0; bb < 16; ++bb) accv[bb] += ys[bb][k] * wv;
    }
    const float b1 = ob1[ctx * HO_ + t];
    const float w2v = ow2[(size_t)ctx * HO_ + t];
    const int lane = t & 63, wv8 = t >> 6;
    #pragma unroll
    for (int bb = 0; bb < 16; ++bb) {
        float s = fmaxf(accv[bb] + b1, 0.0f) * w2v;
        #pragma unroll
        for (int off = 32; off; off >>= 1) s += __shfl_down(s, off);
        if (lane == 0) part[bb][wv8] = s;
    }
    __syncthreads();
    if (t < 16) {
        float s = ob2[ctx];
        #pragma unroll
        for (int w8 = 0; w8 < 8; ++w8) s += part[t][w8];
        out[b0 + t] = s;
    }
}

extern "C" void kernel_launch(void* const* d_in, const int* in_sizes, int n_in,
                              void* d_out, int out_size, void* d_ws, size_t ws_size,
                              hipStream_t stream) {
    (void)in_sizes; (void)n_in; (void)out_size; (void)ws_size;
    const float* inputs = (const float*)d_in[0];
    const float* sw1 = (const float*)d_in[1];
    const float* sb1 = (const float*)d_in[2];
    const float* sw2 = (const float*)d_in[3];
    const float* sb2 = (const float*)d_in[4];
    const float* fw1 = (const float*)d_in[5];
    const float* fb1 = (const float*)d_in[6];
    const float* fw2 = (const float*)d_in[7];
    const float* fb2 = (const float*)d_in[8];
    const float* ow1 = (const float*)d_in[9];
    const float* ob1 = (const float*)d_in[10];
    const float* ow2 = (const float*)d_in[11];
    const float* ob2 = (const float*)d_in[12];
    const int* actp = (const int*)d_in[13];
    const int* ctxp = (const int*)d_in[14];

    char* p = (char*)d_ws;
    unsigned short* w1t = (unsigned short*)p; p += (size_t)E_ * H1_ * TIN_ * 2;
    unsigned short* w2t = (unsigned short*)p; p += (size_t)E_ * S_ * H1_ * 2;
    unsigned short* f1t = (unsigned short*)p; p += (size_t)E_ * H2_ * S_ * 2;
    unsigned short* f2t = (unsigned short*)p; p += (size_t)E_ * F_ * H2_ * 2;
    unsigned short* xbf = (unsigned short*)p; p += (size_t)B_SZ * TIN_ * 2;
    unsigned short* base = (unsigned short*)p; p += (size_t)E_ * B_SZ * H1_ * 2;
    unsigned short* hbf = (unsigned short*)p; p += (size_t)E_ * B_SZ * H1_ * 2;
    unsigned short* stbf = (unsigned short*)p; p += (size_t)E_ * B_SZ * S_ * 2;
    unsigned short* gbf = (unsigned short*)p; p += (size_t)E_ * B_SZ * H2_ * 2;

    cvt_all<<<dim3(968, E_), 256, 0, stream>>>(sw1, sw2, fw1, fw2, w1t, w2t, f1t, f2t);
    x_init<<<(B_SZ * IN_ / 4) / 256, 256, 0, stream>>>(inputs, xbf);

    // base = inputs @ sw1[:, T_:, :] + sb1 (bf16) ; h0 = softplus(base) fused
    // <128,128,512> 16 waves/CU, paired m-blocks share weight panel via L2
    gemm_k<128, 128, 512, 2, 4, 0, 0, 2, true><<<dim3(512), 512, 0, stream>>>(
        xbf, TIN_, 0L, T_, IN_, w1t, TIN_, (long)H1_ * TIN_, sb1, nullptr,
        base, hbf, H1_, (long)B_SZ * H1_, H1_);

    for (int it = 0; it < 4; ++it) {
        if (it > 0) {
            gemm_k<128, 128, 512, 2, 4, 1, 1, 0, true><<<dim3(512), 512, 0, stream>>>(
                xbf, TIN_, 0L, 0, T_, w1t, TIN_, (long)H1_ * TIN_, nullptr, base,
                hbf, nullptr, H1_, (long)B_SZ * H1_, H1_);
        }
        gemm_k<128, 64, 256, 2, 2, 0, 0, 0, true><<<dim3(512), 256, 0, stream>>>(
            hbf, H1_, (long)B_SZ * H1_, 0, H1_, w2t, H1_, (long)S_ * H1_, sb2, nullptr,
            stbf, nullptr, S_, (long)B_SZ * S_, S_);
        if (it < 3) {
            gemm_k<128, 64, 256, 2, 2, 2, 0, 0, true><<<dim3(512), 256, 0, stream>>>(
                stbf, S_, (long)B_SZ * S_, 0, S_, f1t, S_, (long)H2_ * S_, fb1, nullptr,
                gbf, nullptr, H2_, (long)B_SZ * H2_, H2_);
            // feat written straight into x_bf[:, :T_]  (out idx = e*64 + row*TIN_ + col)
            gemm_k<64, 64, 256, 2, 2, 0, 0, 0, false><<<dim3(4, 1, E_), 256, 0, stream>>>(
                gbf, H2_, (long)B_SZ * H2_, 0, H2_, f2t, H2_, (long)F_ * H2_, fb2, nullptr,
                xbf, nullptr, TIN_, 64L, F_);
        }
    }
    head<<<B_SZ / 16, 512, 0, stream>>>(stbf, ow1, ob1, ow2, ob2, actp, ctxp, (float*)d_out);
}